// Round 1
// baseline (194.917 us; speedup 1.0000x reference)
//
#include <hip/hip_runtime.h>
#include <math.h>

#define BATCH 16
#define NCLS 80
#define NANCH 3
#define SUMHW 7581            // 76*76 + 38*38 + 19*19
#define NN (3 * SUMHW)        // 22743 boxes per image
#define TOPK 128
#define CAP 1024

// sigmoid matching a float32 chain with correctly-rounded exp:
// s = 1 / (1 + exp(-x)), exp computed in double then rounded to f32.
__device__ __forceinline__ float sigf(float x) {
    float e = (float)exp(-(double)x);
    return 1.0f / (1.0f + e);
}
__device__ __forceinline__ float expf_cr(float x) {
    return (float)exp((double)x);
}

// ---------------- Stage 1: decode ----------------
__global__ void decode_kernel(const float* __restrict__ pred,
                              float4* __restrict__ boxes,
                              float* __restrict__ probs,
                              int S, int HW, int off,
                              float aw0, float aw1, float aw2,
                              float ah0, float ah1, float ah2) {
    int t = blockIdx.x * blockDim.x + threadIdx.x;
    int total = BATCH * NANCH * HW;
    if (t >= total) return;
    int cell = t % HW;
    int a = (t / HW) % NANCH;
    int b = t / (HW * NANCH);

    const float* pb = pred + ((size_t)b * 255 + (size_t)a * 85) * (size_t)HW + cell;
    float tx  = pb[0];
    float ty  = pb[(size_t)HW];
    float tw  = pb[(size_t)2 * HW];
    float th  = pb[(size_t)3 * HW];
    float obj = pb[(size_t)4 * HW];

    float Sf = (float)S;
    float gx = (float)(cell % S);
    float gy = (float)(cell / S);
    float cx = (sigf(tx) + gx) / Sf;
    float cy = (sigf(ty) + gy) / Sf;
    float aw = (a == 0) ? aw0 : (a == 1) ? aw1 : aw2;
    float ah = (a == 0) ? ah0 : (a == 1) ? ah1 : ah2;
    float bw = expf_cr(tw) * aw;
    float bh = expf_cr(th) * ah;
    float x1 = cx - 0.5f * bw;
    float y1 = cy - 0.5f * bh;
    float x2 = x1 + bw;
    float y2 = y1 + bh;

    int n = a * SUMHW + off + cell;
    boxes[(size_t)b * NN + n] = make_float4(x1, y1, x2, y2);

    float so = sigf(obj);
    float* prow = probs + (size_t)b * NCLS * NN + n;
    for (int c = 0; c < NCLS; ++c) {
        float sc = sigf(pb[(size_t)(5 + c) * HW]);
        prow[(size_t)c * NN] = so * sc;   // raw score; threshold applied in stage 2
    }
}

// ---------------- Stage 2: per-(b,c) top-K select + greedy NMS ----------------
// Suffix-scan 4096-bin shared histogram from the top; find bin where cumulative
// count crosses R. Returns total; crossing thread broadcasts bin & count-above.
__device__ __forceinline__ unsigned int block_suffix_find(
        unsigned int* hist, unsigned int* sums, int t, unsigned int R,
        volatile unsigned int* bc_bin, volatile unsigned int* bc_above) {
    unsigned int sl = 0;
#pragma unroll
    for (int k2 = 0; k2 < 16; ++k2) sl += hist[t * 16 + k2];
    sums[t] = sl;
    __syncthreads();
    for (int d = 1; d < 256; d <<= 1) {
        unsigned int v = sums[t];
        if (t + d < 256) v += sums[t + d];
        __syncthreads();
        sums[t] = v;
        __syncthreads();
    }
    unsigned int total = sums[0];
    unsigned int suf_incl = sums[t];
    unsigned int suf_excl = suf_incl - sl;
    if (R <= total && suf_excl < R && R <= suf_incl) {
        unsigned int acc = suf_excl;
        for (int k2 = 15; k2 >= 0; --k2) {
            unsigned int h = hist[t * 16 + k2];
            if (acc < R && R <= acc + h) { *bc_bin = (unsigned int)(t * 16 + k2); *bc_above = acc; break; }
            acc += h;
        }
    }
    __syncthreads();
    return total;
}

__global__ __launch_bounds__(256) void select_nms_kernel(
        const float* __restrict__ probs,
        const float4* __restrict__ boxes,
        float* __restrict__ out) {
    __shared__ unsigned long long sbuf[2048];   // 16KB: hist(uint[4096]) then skey(u64[1024])
    unsigned int* hist = (unsigned int*)sbuf;
    unsigned long long* skey = sbuf;
    __shared__ unsigned int sums[256];
    __shared__ float bxs[TOPK][4];
    __shared__ float areas[TOPK];
    __shared__ float pv[TOPK];
    __shared__ unsigned int bc_bin, bc_above, gcount;

    int t = threadIdx.x;
    int bid = blockIdx.x;               // b*80 + c
    int b = bid / NCLS;
    int c = bid % NCLS;
    const float* row = probs + (size_t)bid * NN;
    const float4* brow = boxes + (size_t)b * NN;

    // --- phase 1 histogram: top 12 bits of positive-float key ---
    for (int i = t; i < 4096; i += 256) hist[i] = 0;
    __syncthreads();
    for (int n = t; n < NN; n += 256) {
        float v = row[n];
        if (v > 0.3f) atomicAdd(&hist[__float_as_uint(v) >> 20], 1u);
    }
    __syncthreads();
    unsigned int total = block_suffix_find(hist, sums, t, TOPK, &bc_bin, &bc_above);

    unsigned int prefix;
    if (total <= CAP) {
        prefix = 0;                       // gather all candidates
    } else {
        unsigned int B1 = bc_bin, above1 = bc_above;
        unsigned int cnt1 = hist[B1];
        if (above1 + cnt1 <= CAP) {
            prefix = B1 << 20;
        } else {
            // --- phase 2 refine: bits [19:8] within bin B1 ---
            __syncthreads();
            for (int i = t; i < 4096; i += 256) hist[i] = 0;
            __syncthreads();
            for (int n = t; n < NN; n += 256) {
                float v = row[n];
                if (v > 0.3f) {
                    unsigned int k = __float_as_uint(v);
                    if ((k >> 20) == B1) atomicAdd(&hist[(k >> 8) & 0xFFFu], 1u);
                }
            }
            __syncthreads();
            unsigned int R2 = TOPK - above1;
            block_suffix_find(hist, sums, t, R2, &bc_bin, &bc_above);
            prefix = (B1 << 20) | (bc_bin << 8);
        }
    }
    __syncthreads();   // everyone done with hist before reusing as skey

    // --- gather candidates with key >= prefix ---
    if (t == 0) gcount = 0;
    __syncthreads();
    for (int n = t; n < NN; n += 256) {
        float v = row[n];
        if (v > 0.3f) {
            unsigned int k = __float_as_uint(v);
            if (k >= prefix) {
                unsigned int pos = atomicAdd(&gcount, 1u);
                if (pos < CAP)
                    skey[pos] = ((unsigned long long)k << 32) | (unsigned int)(~(unsigned int)n);
            }
        }
    }
    __syncthreads();
    unsigned int Gc = gcount < CAP ? gcount : CAP;

    // --- bitonic sort descending on (score_bits, ~idx) ---
    int M = TOPK;
    while ((unsigned int)M < Gc) M <<= 1;
    for (int i = t; i < M; i += 256) if (i >= (int)Gc) skey[i] = 0ULL;
    __syncthreads();
    for (int k = 2; k <= M; k <<= 1) {
        for (int j = k >> 1; j > 0; j >>= 1) {
            for (int i = t; i < M; i += 256) {
                int l = i ^ j;
                if (l > i) {
                    unsigned long long a0 = skey[i], a1 = skey[l];
                    bool sw = ((i & k) == 0) ? (a0 < a1) : (a0 > a1);
                    if (sw) { skey[i] = a1; skey[l] = a0; }
                }
            }
            __syncthreads();
        }
    }

    // --- extract top-128 ---
    for (int i = t; i < TOPK; i += 256) {
        bool valid = (i < (int)Gc);
        unsigned long long e = valid ? skey[i] : 0ULL;
        float sc = __uint_as_float((unsigned int)(e >> 32));
        unsigned int n = ~(unsigned int)(e & 0xFFFFFFFFu);
        float4 bb = make_float4(0.f, 0.f, 0.f, 0.f);
        if (valid) bb = brow[n];
        bxs[i][0] = bb.x; bxs[i][1] = bb.y; bxs[i][2] = bb.z; bxs[i][3] = bb.w;
        areas[i] = (bb.z - bb.x) * (bb.w - bb.y);
        pv[i] = valid ? sc : -1.0f;
    }
    __syncthreads();

    // --- greedy NMS: 128 serial steps, parallel over j ---
    for (int i = 0; i < TOPK; ++i) {
        float pi = pv[i];
        if (pi > 0.0f) {
            float xi1 = bxs[i][0], yi1 = bxs[i][1], xi2 = bxs[i][2], yi2 = bxs[i][3];
            float ai = areas[i];
            for (int j = t; j < TOPK; j += 256) {
                if (j > i) {
                    float xx1 = fmaxf(xi1, bxs[j][0]);
                    float yy1 = fmaxf(yi1, bxs[j][1]);
                    float xx2 = fminf(xi2, bxs[j][2]);
                    float yy2 = fminf(yi2, bxs[j][3]);
                    float ww = fmaxf(xx2 - xx1, 0.0f);
                    float hh = fmaxf(yy2 - yy1, 0.0f);
                    float inter = ww * hh;
                    float iou = inter / (ai + areas[j] - inter);
                    if (iou > 0.45f) pv[j] = -1.0f;
                }
            }
        }
        __syncthreads();
    }

    // --- write [K,6] = x1,y1,x2,y2,score,class ---
    float* o = out + (size_t)bid * TOPK * 6;
    for (int i = t; i < TOPK; i += 256) {
        bool kept = pv[i] > 0.0f;
        o[i * 6 + 0] = kept ? bxs[i][0] : 0.0f;
        o[i * 6 + 1] = kept ? bxs[i][1] : 0.0f;
        o[i * 6 + 2] = kept ? bxs[i][2] : 0.0f;
        o[i * 6 + 3] = kept ? bxs[i][3] : 0.0f;
        o[i * 6 + 4] = kept ? pv[i] : 0.0f;
        o[i * 6 + 5] = (float)c;
    }
}

extern "C" void kernel_launch(void* const* d_in, const int* in_sizes, int n_in,
                              void* d_out, int out_size, void* d_ws, size_t ws_size,
                              hipStream_t stream) {
    const float* preds[3] = { (const float*)d_in[0], (const float*)d_in[1], (const float*)d_in[2] };
    float* out = (float*)d_out;

    char* ws = (char*)d_ws;
    float4* boxes = (float4*)ws;                                   // 16*22743*16B = 5.82 MB
    float*  probs = (float*)(ws + (size_t)BATCH * NN * sizeof(float4)); // 16*80*22743*4B = 116.4 MB

    static const float ANC[3][3][2] = {
        {{12, 16}, {19, 36}, {40, 28}},
        {{36, 75}, {76, 55}, {72, 146}},
        {{142, 110}, {192, 243}, {459, 401}},
    };
    static const int RED[3] = {8, 16, 32};
    static const int SS[3]  = {76, 38, 19};
    static const int OFF[3] = {0, 5776, 7220};

    for (int s = 0; s < 3; ++s) {
        int S = SS[s];
        int HW = S * S;
        float Sf = (float)S;
        float aw[3], ah[3];
        for (int a = 0; a < 3; ++a) {
            aw[a] = (ANC[s][a][0] / (float)RED[s]) / Sf;   // exact /red, then f32 /S (matches ref)
            ah[a] = (ANC[s][a][1] / (float)RED[s]) / Sf;
        }
        int total = BATCH * NANCH * HW;
        int blocks = (total + 255) / 256;
        decode_kernel<<<blocks, 256, 0, stream>>>(preds[s], boxes, probs,
                                                  S, HW, OFF[s],
                                                  aw[0], aw[1], aw[2],
                                                  ah[0], ah[1], ah[2]);
    }

    select_nms_kernel<<<BATCH * NCLS, 256, 0, stream>>>(probs, boxes, out);
}